// Round 9
// baseline (486.212 us; speedup 1.0000x reference)
//
#include <hip/hip_runtime.h>
#include <cfloat>

#define N_TOK   32768
#define DIM     64
#define K_CODES 8192
#define NCHK    32                 // 256-code chunks per token

#define IDX_OFF  (N_TOK * DIM)
#define LOSS_OFF (N_TOK * DIM + N_TOK)

// ws layout (float units) — total 532608 floats, <= proven R3-R7 footprint
#define WS_ESQ   0
#define WS_MM    8192              // 32768*32 ushorts = 524288 float slots
#define WS_PART  (8192 + 524288)   // 128 floats

#define MRG   3e-5f                // strict slack: bound < every computed d in chunk

typedef __attribute__((ext_vector_type(8)))  short bf16x8;
typedef __attribute__((ext_vector_type(16))) float f32x16;

__device__ inline ushort f2bf(float x) {          // round-to-nearest-even
    unsigned u = __float_as_uint(x);
    return (ushort)((u + 0x7FFFu + ((u >> 16) & 1u)) >> 16);
}
__device__ inline float bf2f(ushort h) { return __uint_as_float(((unsigned)h) << 16); }
__device__ inline ushort f2bf_up(float x) {       // round toward +inf (conservative)
    unsigned u = __float_as_uint(x);
    return (x >= 0.0f) ? (ushort)((u + 0xFFFFu) >> 16) : (ushort)(u >> 16);
}

// ---------------------------------------------------------------------------
// e_sq[k] = numpy-pairwise sum of squares (bitwise np order) — proven R1-R7.
// ---------------------------------------------------------------------------
__global__ __launch_bounds__(256) void esq_kernel(const float* __restrict__ emb,
                                                  float* __restrict__ esq) {
#pragma clang fp contract(off)
    const int tid = threadIdx.x;
    const int q = tid & 7;
    const int code = blockIdx.x * 32 + (tid >> 3);
    const float* row = emb + code * DIM;
    float x = row[q];
    float r = x * x;
#pragma unroll
    for (int m = 1; m < 8; ++m) {
        float y = row[q + 8 * m];
        float sq = y * y;
        r = r + sq;
    }
    r = r + __shfl_xor(r, 1, 64);
    r = r + __shfl_xor(r, 2, 64);
    r = r + __shfl_xor(r, 4, 64);
    if (q == 0) esq[code] = r;
}

// ---------------------------------------------------------------------------
// MFMA sweep: block = 64 tokens; per 128-code subchunk each wave owns 32 codes.
// dot~ = z_hi*e_bf + z_lo*e_bf (folded accumulator). Per-token max over each
// 256-code chunk -> Mm[token][chunk] as round-UP bf16 (conservative).
// C/D layout (m74/m101 HW-verified): col=lane&31, row=(reg&3)+8(reg>>2)+4(lane>>5).
// ---------------------------------------------------------------------------
__global__ __launch_bounds__(256) void vq_mfma(const float* __restrict__ hid,
                                               const float* __restrict__ emb,
                                               ushort* __restrict__ Mm) {
    __shared__ ushort ebuf[2][128 * 72];   // stride 72 ushorts (144B): bank-balanced
    __shared__ float tmw[4][64];

    const int tid = threadIdx.x;
    const int lane = tid & 63;
    const int w = tid >> 6;
    const int h = lane >> 5;
    const int t0 = blockIdx.x * 64;

    // ---- A fragments: z hi/lo, 2 token-subtiles x 4 K-steps ----
    bf16x8 a_hi[2][4], a_lo[2][4];
#pragma unroll
    for (int ts = 0; ts < 2; ++ts)
#pragma unroll
    for (int q = 0; q < 4; ++q) {
        const float* zp = hid + (size_t)(t0 + 32 * ts + (lane & 31)) * DIM + 16 * q + 8 * h;
        const float4 u0 = *(const float4*)zp;
        const float4 u1 = *(const float4*)(zp + 4);
        const float zz[8] = {u0.x, u0.y, u0.z, u0.w, u1.x, u1.y, u1.z, u1.w};
        bf16x8 hv, lv;
#pragma unroll
        for (int i = 0; i < 8; ++i) {
            const ushort hb = f2bf(zz[i]);
            hv[i] = (short)hb;
            lv[i] = (short)f2bf(zz[i] - bf2f(hb));
        }
        a_hi[ts][q] = hv; a_lo[ts][q] = lv;
    }

    f32x16 z16;
#pragma unroll
    for (int i = 0; i < 16; ++i) z16[i] = 0.0f;

    const int sr = tid >> 1;        // staging row 0..127
    const int sh = tid & 1;         // dim half

    float4 pref[8];
    // prologue: stage sc0 into buf0; prefetch sc1
    {
        const float4* src = (const float4*)(emb + (size_t)sr * DIM + 32 * sh);
#pragma unroll
        for (int i = 0; i < 8; ++i) pref[i] = src[i];
        ushort* dst = &ebuf[0][72 * sr + 32 * sh];
        const float* pf = (const float*)pref;
#pragma unroll
        for (int i = 0; i < 4; ++i) {
            bf16x8 v;
#pragma unroll
            for (int e = 0; e < 8; ++e) v[e] = (short)f2bf(pf[8 * i + e]);
            *(bf16x8*)(dst + 8 * i) = v;
        }
        const float4* s2 = (const float4*)(emb + (size_t)(128 + sr) * DIM + 32 * sh);
#pragma unroll
        for (int i = 0; i < 8; ++i) pref[i] = s2[i];
    }
    __syncthreads();

    float wm0[16], wm1[16];
#pragma unroll
    for (int i = 0; i < 16; ++i) { wm0[i] = -3.0e38f; wm1[i] = -3.0e38f; }

    const int kloc = 32 * w + (lane & 31);

    for (int sc = 0; sc < 64; ++sc) {
        const int b = sc & 1;
        const ushort* eb = &ebuf[b][0];
        f32x16 d0, d1;
#pragma unroll
        for (int q = 0; q < 4; ++q) {
            const bf16x8 bq = *(const bf16x8*)(eb + 72 * kloc + 16 * q + 8 * h);
            if (q == 0) {
                d0 = __builtin_amdgcn_mfma_f32_32x32x16_bf16(a_hi[0][0], bq, z16, 0, 0, 0);
                d1 = __builtin_amdgcn_mfma_f32_32x32x16_bf16(a_hi[1][0], bq, z16, 0, 0, 0);
            } else {
                d0 = __builtin_amdgcn_mfma_f32_32x32x16_bf16(a_hi[0][q], bq, d0, 0, 0, 0);
                d1 = __builtin_amdgcn_mfma_f32_32x32x16_bf16(a_hi[1][q], bq, d1, 0, 0, 0);
            }
            d0 = __builtin_amdgcn_mfma_f32_32x32x16_bf16(a_lo[0][q], bq, d0, 0, 0, 0);
            d1 = __builtin_amdgcn_mfma_f32_32x32x16_bf16(a_lo[1][q], bq, d1, 0, 0, 0);
        }
#pragma unroll
        for (int i = 0; i < 16; ++i) {
            wm0[i] = fmaxf(wm0[i], d0[i]);
            wm1[i] = fmaxf(wm1[i], d1[i]);
        }

        if (sc & 1) {   // chunk boundary: per-token reduce over this wave's 32 codes
#pragma unroll
            for (int i = 0; i < 16; ++i) {
                float v0 = wm0[i], v1 = wm1[i];
#pragma unroll
                for (int m = 1; m < 32; m <<= 1) {
                    v0 = fmaxf(v0, __shfl_xor(v0, m, 64));
                    v1 = fmaxf(v1, __shfl_xor(v1, m, 64));
                }
                if ((lane & 31) == 0) {
                    const int rb = (i & 3) + 8 * (i >> 2) + 4 * h;
                    tmw[w][rb] = v0;
                    tmw[w][32 + rb] = v1;
                }
                wm0[i] = -3.0e38f; wm1[i] = -3.0e38f;
            }
        }
        __syncthreads();
        if ((sc & 1) && tid < 64) {
            const float m4 = fmaxf(fmaxf(tmw[0][tid], tmw[1][tid]),
                                   fmaxf(tmw[2][tid], tmw[3][tid]));
            Mm[(size_t)(t0 + tid) * NCHK + (sc >> 1)] = f2bf_up(m4);
        }
        if (sc + 1 < 64) {   // write prefetched subchunk (convert f32->bf16)
            ushort* dst = &ebuf[b ^ 1][72 * sr + 32 * sh];
            const float* pf = (const float*)pref;
#pragma unroll
            for (int i = 0; i < 4; ++i) {
                bf16x8 v;
#pragma unroll
                for (int e = 0; e < 8; ++e) v[e] = (short)f2bf(pf[8 * i + e]);
                *(bf16x8*)(dst + 8 * i) = v;
            }
        }
        if (sc + 2 < 64) {   // issue next global loads (hide under next compute)
            const float4* src = (const float4*)(emb + (size_t)((sc + 2) * 128 + sr) * DIM + 32 * sh);
#pragma unroll
            for (int i = 0; i < 8; ++i) pref[i] = src[i];
        }
        __syncthreads();
    }
}

// ---------------------------------------------------------------------------
// Exact selection: block = 128 tokens. Per 256-code chunk, list tokens whose
// conservative bound can beat their current best; survivors evaluated with the
// ref-bitwise chain. bound < every computed d in chunk (strict MRG slack) =>
// skipping never loses an equal-distance smaller index.
// ---------------------------------------------------------------------------
__global__ __launch_bounds__(256) void vq_select(const float* __restrict__ hid,
                                                 const float* __restrict__ emb,
                                                 const float* __restrict__ esq,
                                                 const ushort* __restrict__ Mm,
                                                 float* __restrict__ out_idx) {
#pragma clang fp contract(off)
    __shared__ float e_s[128 * 76];   // stride 76 floats (304B): aligned + bank-balanced
    __shared__ float bestL[128];
    __shared__ int   bestiL[128];
    __shared__ float zsq_s[128];
    __shared__ float eps_s[128];
    __shared__ int   list[128];
    __shared__ int   cnt;

    const int tid = threadIdx.x;
    const int lane = tid & 63;
    const int w = tid >> 6;
    const int t0 = blockIdx.x * 128;

    // ---- phase 0: zsq (numpy pairwise), per-token eps, best init from Mm ----
    if (tid < 128) {
        const int t = t0 + tid;
        const float4* zp = (const float4*)(hid + (size_t)t * DIM);
        float z[64];
#pragma unroll
        for (int i = 0; i < 16; ++i) {
            const float4 v = zp[i];
            z[4 * i] = v.x; z[4 * i + 1] = v.y; z[4 * i + 2] = v.z; z[4 * i + 3] = v.w;
        }
        float r[8];
#pragma unroll
        for (int q = 0; q < 8; ++q) {
            float x = z[q]; r[q] = x * x;
#pragma unroll
            for (int m = 1; m < 8; ++m) {
                float y = z[q + 8 * m];
                float sq = y * y;
                r[q] = r[q] + sq;
            }
        }
        const float zsq = ((r[0] + r[1]) + (r[2] + r[3])) + ((r[4] + r[5]) + (r[6] + r[7]));
        const ushort* mr = Mm + (size_t)t * NCHK;
        float mx = bf2f(mr[0]);
#pragma unroll
        for (int c = 1; c < NCHK; ++c) mx = fmaxf(mx, bf2f(mr[c]));
        const float eps = sqrtf(zsq) * 3.82e-6f + 5e-7f;   // |z|2*|e|2max*2^-8 + slack
        zsq_s[tid] = zsq;
        eps_s[tid] = eps;
        bestL[tid] = zsq - 2.0f * mx + 2.0f * eps + 8e-5f; // >= computed best distance
        bestiL[tid] = 0;
    }

    for (int c = 0; c < NCHK; ++c) {
        __syncthreads();
        if (tid == 0) cnt = 0;
        __syncthreads();
        if (tid < 128) {
            const float m = bf2f(Mm[(size_t)(t0 + tid) * NCHK + c]);
            const float bound = fmaf(-2.0f, m + eps_s[tid], zsq_s[tid]) - MRG;
            if (bound < bestL[tid]) { const int p = atomicAdd(&cnt, 1); list[p] = tid; }
        }
        __syncthreads();
        const int nl = cnt;
        if (nl == 0) continue;

        for (int s = 0; s < 2; ++s) {      // two 128-code slices of the chunk
            {   // stage slice into LDS
                const int r2 = tid >> 1, hh = tid & 1;
                const float4* src = (const float4*)(
                    emb + (size_t)(c * 256 + s * 128 + r2) * DIM + 32 * hh);
                float* dst = e_s + 76 * r2 + 32 * hh;
#pragma unroll
                for (int i = 0; i < 8; ++i) *(float4*)(dst + 4 * i) = src[i];
            }
            __syncthreads();
            for (int i = w; i < nl; i += 4) {            // wave per listed token
                const int tt = __builtin_amdgcn_readfirstlane(list[i]);
                const float zq = zsq_s[tt];
                const float4* zp = (const float4*)(hid + (size_t)(t0 + tt) * DIM);
                float z[64];
#pragma unroll
                for (int i2 = 0; i2 < 16; ++i2) {
                    const float4 v = zp[i2];
                    z[4 * i2] = v.x; z[4 * i2 + 1] = v.y;
                    z[4 * i2 + 2] = v.z; z[4 * i2 + 3] = v.w;
                }
                float dl = 3.0e38f; int il = 0;
#pragma unroll
                for (int rr = 0; rr < 2; ++rr) {
                    const int row = 64 * rr + lane;
                    const int k = c * 256 + s * 128 + row;
                    const float* er = e_s + 76 * row;
                    float ev[64];
#pragma unroll
                    for (int i2 = 0; i2 < 16; ++i2) {
                        const float4 v = *(const float4*)(er + 4 * i2);
                        ev[4 * i2] = v.x; ev[4 * i2 + 1] = v.y;
                        ev[4 * i2 + 2] = v.z; ev[4 * i2 + 3] = v.w;
                    }
                    float acc = z[0] * ev[0];
#pragma unroll
                    for (int j = 1; j < DIM; ++j) acc = fmaf(z[j], ev[j], acc);
                    const float sA = zq + esq[k];
                    const float d = fmaf(-2.0f, acc, sA);
                    if (d < dl) { dl = d; il = k; }
                }
#pragma unroll
                for (int m = 1; m < 64; m <<= 1) {
                    const float ov = __shfl_xor(dl, m, 64);
                    const int   oi = __shfl_xor(il, m, 64);
                    if (ov < dl || (ov == dl && oi < il)) { dl = ov; il = oi; }
                }
                if (lane == 0 && dl < bestL[tt]) { bestL[tt] = dl; bestiL[tt] = il; }
            }
            __syncthreads();
        }
    }

    __syncthreads();
    if (tid < 128) out_idx[t0 + tid] = (float)bestiL[tid];
}

// ---------------------------------------------------------------------------
// Outputs: z_q = h + (q - h), loss partials (proven form; idx read from d_out).
// ---------------------------------------------------------------------------
__global__ __launch_bounds__(256) void vq_finish(const float* __restrict__ hid,
                                                 const float* __restrict__ emb,
                                                 const float* __restrict__ out_idx,
                                                 float* __restrict__ out_zq,
                                                 float* __restrict__ partials) {
#pragma clang fp contract(off)
    __shared__ float lred[4];
    const int tid = threadIdx.x;
    const int t = blockIdx.x * 256 + tid;

    const int bi = (int)out_idx[t];

    const float4* q4 = (const float4*)(emb + (size_t)bi * DIM);
    const float4* h4 = (const float4*)(hid + (size_t)t * DIM);
    float4* o4 = (float4*)(out_zq + (size_t)t * DIM);
    float lsum = 0.f;
#pragma unroll
    for (int i = 0; i < 16; ++i) {
        const float4 q = q4[i];
        const float4 h = h4[i];
        float4 zq;
        float dx;
        dx = q.x - h.x; zq.x = h.x + dx; lsum += dx * dx;
        dx = q.y - h.y; zq.y = h.y + dx; lsum += dx * dx;
        dx = q.z - h.z; zq.z = h.z + dx; lsum += dx * dx;
        dx = q.w - h.w; zq.w = h.w + dx; lsum += dx * dx;
        o4[i] = zq;
    }

#pragma unroll
    for (int off = 32; off >= 1; off >>= 1) lsum += __shfl_xor(lsum, off, 64);
    const int wid = tid >> 6;
    if ((tid & 63) == 0) lred[wid] = lsum;
    __syncthreads();
    if (tid == 0) partials[blockIdx.x] = (lred[0] + lred[1]) + (lred[2] + lred[3]);
}

__global__ __launch_bounds__(128) void loss_kernel(const float* __restrict__ partials,
                                                   float* __restrict__ out_loss) {
#pragma clang fp contract(off)
    __shared__ float s[128];
    const int t = threadIdx.x;
    s[t] = partials[t];
    __syncthreads();
    for (int off = 64; off >= 1; off >>= 1) {
        if (t < off) s[t] = s[t] + s[t + off];
        __syncthreads();
    }
    if (t == 0) {
        const float m = s[0] * (1.0f / 2097152.0f);  // exact: /2^21
        out_loss[0] = m + 0.25f * m;
    }
}

extern "C" void kernel_launch(void* const* d_in, const int* in_sizes, int n_in,
                              void* d_out, int out_size, void* d_ws, size_t ws_size,
                              hipStream_t stream) {
    const float* hid = (const float*)d_in[0];
    const float* emb = (const float*)d_in[1];
    float* out = (float*)d_out;
    float* ws  = (float*)d_ws;
    float*  esq   = ws + WS_ESQ;
    ushort* Mm    = (ushort*)(ws + WS_MM);
    float*  parts = ws + WS_PART;

    esq_kernel<<<K_CODES / 32, 256, 0, stream>>>(emb, esq);
    vq_mfma<<<N_TOK / 64, 256, 0, stream>>>(hid, emb, Mm);
    vq_select<<<N_TOK / 128, 256, 0, stream>>>(hid, emb, esq, Mm, out + IDX_OFF);
    vq_finish<<<N_TOK / 256, 256, 0, stream>>>(hid, emb, out + IDX_OFF,
                                               out, parts);
    loss_kernel<<<1, 128, 0, stream>>>(parts, out + LOSS_OFF);
}

// Round 10
// 282.530 us; speedup vs baseline: 1.7209x; 1.7209x over previous
//
#include <hip/hip_runtime.h>
#include <cfloat>

#define N_TOK   32768
#define DIM     64
#define K_CODES 8192
#define NCHK    32                 // 256-code chunks

#define IDX_OFF  (N_TOK * DIM)
#define LOSS_OFF (N_TOK * DIM + N_TOK)

// ws layout (float units): esq 8192 + ehi 262144 (1MB of bf16) + parts 128
#define WS_ESQ   0
#define WS_EHI   8192
#define WS_PART  270336

#define MRG   2e-5f     // strict slack: bound < every computed fl-d in chunk
#define DINIT 3e-5f     // init upper-bound slack (esq_max 1e-6 + 2 fl-roundings + margin)

typedef __attribute__((ext_vector_type(8)))  short bf16x8;
typedef __attribute__((ext_vector_type(16))) float f32x16;

__device__ inline ushort f2bf(float x) {          // round-to-nearest-even
    unsigned u = __float_as_uint(x);
    return (ushort)((u + 0x7FFFu + ((u >> 16) & 1u)) >> 16);
}
__device__ inline float bf2f(ushort h) { return __uint_as_float(((unsigned)h) << 16); }

// ---------------------------------------------------------------------------
// e_sq[k] = numpy-pairwise sum of squares (bitwise np order) — proven R1-R9.
// ---------------------------------------------------------------------------
__global__ __launch_bounds__(256) void esq_kernel(const float* __restrict__ emb,
                                                  float* __restrict__ esq) {
#pragma clang fp contract(off)
    const int tid = threadIdx.x;
    const int q = tid & 7;
    const int code = blockIdx.x * 32 + (tid >> 3);
    const float* row = emb + code * DIM;
    float x = row[q];
    float r = x * x;
#pragma unroll
    for (int m = 1; m < 8; ++m) {
        float y = row[q + 8 * m];
        float sq = y * y;
        r = r + sq;
    }
    r = r + __shfl_xor(r, 1, 64);
    r = r + __shfl_xor(r, 2, 64);
    r = r + __shfl_xor(r, 4, 64);
    if (q == 0) esq[code] = r;
}

// ---------------------------------------------------------------------------
// Pack embedding rows to bf16 (RN) once: ehi[k][d], code-major 128B rows.
// ---------------------------------------------------------------------------
__global__ __launch_bounds__(256) void pack_hi(const float* __restrict__ emb,
                                               ushort* __restrict__ ehi) {
#pragma clang fp contract(off)
    const int k = blockIdx.x * 256 + threadIdx.x;     // grid 32 -> 8192 codes
    const float4* ep = (const float4*)(emb + (size_t)k * DIM);
    ushort* op = ehi + (size_t)k * DIM;
#pragma unroll
    for (int i = 0; i < 8; ++i) {
        const float4 a = ep[2 * i], b = ep[2 * i + 1];
        const float zz[8] = {a.x, a.y, a.z, a.w, b.x, b.y, b.z, b.w};
        bf16x8 v;
#pragma unroll
        for (int e = 0; e < 8; ++e) v[e] = (short)f2bf(zz[e]);
        *(bf16x8*)(op + 8 * i) = v;
    }
}

// ---------------------------------------------------------------------------
// MFMA sweep (transposed: A=e from global bf16, B=z hi/lo in regs).
// Block = 64 tokens; wave w owns codes {sc*128 + 32w + (lane&31)}.
// C cols = tokens (col=lane&31, HW-verified); rows = codes -> per-token max
// over a chunk = 15 in-reg fmax + 1 shfl_xor(32). Mm[token][chunk] f32 in
// d_out scratch. dot~ = (z_hi + z_lo) * e_bf16; eps covers e-side bf16 error.
// ---------------------------------------------------------------------------
__global__ __launch_bounds__(256, 2) void vq_mfma(const float* __restrict__ hid,
                                                  const ushort* __restrict__ ehi,
                                                  float* __restrict__ Mm) {
#pragma clang fp contract(off)
    __shared__ float tmw[4][64];

    const int tid = threadIdx.x;
    const int lane = tid & 63;
    const int w = tid >> 6;
    const int h = lane >> 5;
    const int t0 = blockIdx.x * 64;

    // ---- B fragments: z hi/lo, 2 token-sets x 4 K-steps (R9-proven build) ----
    bf16x8 z_hi[2][4], z_lo[2][4];
#pragma unroll
    for (int ts = 0; ts < 2; ++ts)
#pragma unroll
    for (int q = 0; q < 4; ++q) {
        const float* zp = hid + (size_t)(t0 + 32 * ts + (lane & 31)) * DIM + 16 * q + 8 * h;
        const float4 u0 = *(const float4*)zp;
        const float4 u1 = *(const float4*)(zp + 4);
        const float zz[8] = {u0.x, u0.y, u0.z, u0.w, u1.x, u1.y, u1.z, u1.w};
        bf16x8 hv, lv;
#pragma unroll
        for (int i = 0; i < 8; ++i) {
            const ushort hb = f2bf(zz[i]);
            hv[i] = (short)hb;
            lv[i] = (short)f2bf(zz[i] - bf2f(hb));
        }
        z_hi[ts][q] = hv; z_lo[ts][q] = lv;
    }

    f32x16 zc;
#pragma unroll
    for (int i = 0; i < 16; ++i) zc[i] = 0.0f;

    // A-operand addressing: code = sc*128 + 32w + (lane&31), k-octet = 16q+8h
    const size_t arow = (size_t)(32 * w + (lane & 31)) * DIM + 16 * 0 + 8 * h;
    const ushort* abase = ehi + (size_t)(32 * w + (lane & 31)) * DIM + 8 * h;
    (void)arow;

    bf16x8 a_cur[4], a_nxt[4];
#pragma unroll
    for (int q = 0; q < 4; ++q)
        a_cur[q] = *(const bf16x8*)(abase + 16 * q);

    float wm0 = -3.0e38f, wm1 = -3.0e38f;

    for (int sc = 0; sc < 64; ++sc) {
        // prefetch next subchunk's A fragments (clamped)
        const int scn = (sc + 1 < 64) ? (sc + 1) : 63;
#pragma unroll
        for (int q = 0; q < 4; ++q)
            a_nxt[q] = *(const bf16x8*)(abase + (size_t)scn * 128 * DIM + 16 * q);

        f32x16 d0, d1;
#pragma unroll
        for (int q = 0; q < 4; ++q) {
            if (q == 0) {
                d0 = __builtin_amdgcn_mfma_f32_32x32x16_bf16(a_cur[0], z_hi[0][0], zc, 0, 0, 0);
                d1 = __builtin_amdgcn_mfma_f32_32x32x16_bf16(a_cur[0], z_hi[1][0], zc, 0, 0, 0);
            } else {
                d0 = __builtin_amdgcn_mfma_f32_32x32x16_bf16(a_cur[q], z_hi[0][q], d0, 0, 0, 0);
                d1 = __builtin_amdgcn_mfma_f32_32x32x16_bf16(a_cur[q], z_hi[1][q], d1, 0, 0, 0);
            }
            d0 = __builtin_amdgcn_mfma_f32_32x32x16_bf16(a_cur[q], z_lo[0][q], d0, 0, 0, 0);
            d1 = __builtin_amdgcn_mfma_f32_32x32x16_bf16(a_cur[q], z_lo[1][q], d1, 0, 0, 0);
        }
#pragma unroll
        for (int i = 0; i < 16; ++i) {
            wm0 = fmaxf(wm0, d0[i]);
            wm1 = fmaxf(wm1, d1[i]);
        }

        if (sc & 1) {   // chunk boundary: combine row-halves, then waves
            wm0 = fmaxf(wm0, __shfl_xor(wm0, 32, 64));
            wm1 = fmaxf(wm1, __shfl_xor(wm1, 32, 64));
            if (lane < 32) {
                tmw[w][lane] = wm0;
                tmw[w][32 + lane] = wm1;
            }
            __syncthreads();
            if (tid < 64) {
                const float m4 = fmaxf(fmaxf(tmw[0][tid], tmw[1][tid]),
                                       fmaxf(tmw[2][tid], tmw[3][tid]));
                Mm[(size_t)(t0 + tid) * NCHK + (sc >> 1)] = m4;
            }
            __syncthreads();
            wm0 = -3.0e38f; wm1 = -3.0e38f;
        }
#pragma unroll
        for (int q = 0; q < 4; ++q) a_cur[q] = a_nxt[q];
    }
}

// ---------------------------------------------------------------------------
// Exact selection: block = 64 tokens, 4 waves. Per chunk: bound-check ->
// survivor list -> waves batch-eval up to 8 tokens against e rows held in
// REGISTERS (2 rows/lane, read once per batch). Ref-bitwise chains; strict
// MRG makes pruning first-index-safe. Unique writer per (slice,token) slot.
// ---------------------------------------------------------------------------
__global__ __launch_bounds__(256, 2) void vq_select(const float* __restrict__ hid,
                                                    const float* __restrict__ emb,
                                                    const float* __restrict__ esq,
                                                    const float* __restrict__ Mm,
                                                    float* __restrict__ out_idx) {
#pragma clang fp contract(off)
    __shared__ float z_s[64][68];
    __shared__ float zsq_s[64];
    __shared__ float bD[64];
    __shared__ int   bI[64];
    __shared__ float d2s[2][64];
    __shared__ int   i2s[2][64];
    __shared__ int   list[64];
    __shared__ int   cnt;

    const int tid = threadIdx.x;
    const int lane = tid & 63;
    const int w = tid >> 6;
    const int t0 = blockIdx.x * 64;

    // ---- stage z into LDS ----
    {
        const int t = tid >> 2;
        const int j4 = (tid & 3) * 4;          // float4 index
        const float4* src = (const float4*)(hid + (size_t)(t0 + t) * DIM);
        float4* dst = (float4*)(&z_s[t][0]);
#pragma unroll
        for (int i = 0; i < 4; ++i) dst[j4 + i] = src[j4 + i];
    }
    __syncthreads();

    // ---- per-token: zsq (numpy pairwise), best init from Mm row max ----
    if (tid < 64) {
        const float* zr = &z_s[tid][0];
        float r[8];
#pragma unroll
        for (int q = 0; q < 8; ++q) {
            float x = zr[q]; r[q] = x * x;
#pragma unroll
            for (int m = 1; m < 8; ++m) {
                float y = zr[q + 8 * m];
                float sq = y * y;
                r[q] = r[q] + sq;
            }
        }
        const float zsq = ((r[0] + r[1]) + (r[2] + r[3])) + ((r[4] + r[5]) + (r[6] + r[7]));
        const float* mr = Mm + (size_t)(t0 + tid) * NCHK;
        float mx = mr[0];
#pragma unroll
        for (int c = 1; c < NCHK; ++c) mx = fmaxf(mx, mr[c]);
        const float eps = sqrtf(zsq) * 2.5e-6f + 2e-7f;
        zsq_s[tid] = zsq;
        bD[tid] = zsq - 2.0f * mx + 2.0f * eps + DINIT;   // >= true best fl-d
        bI[tid] = 0;
    }

    for (int c = 0; c < NCHK; ++c) {
        if (tid < 128) { d2s[tid >> 6][tid & 63] = 3.0e38f; i2s[tid >> 6][tid & 63] = 0; }
        if (tid == 0) cnt = 0;
        __syncthreads();
        if (tid < 64) {
            const float zsq = zsq_s[tid];
            const float eps = sqrtf(zsq) * 2.5e-6f + 2e-7f;
            const float m = Mm[(size_t)(t0 + tid) * NCHK + c];
            const float bound = fmaf(-2.0f, m + eps, zsq) - MRG;
            if (bound < bD[tid]) { const int p = atomicAdd(&cnt, 1); list[p] = tid; }
        }
        __syncthreads();
        const int nl = cnt;
        const int nb = (nl + 7) >> 3;

        for (int task = w; task < 2 * nb; task += 4) {
            const int b = task >> 1, s = task & 1;
            const int k0 = c * 256 + s * 128 + lane;
            const int k1 = k0 + 64;
            float eA[64], eB[64];
            {
                const float4* pA = (const float4*)(emb + (size_t)k0 * DIM);
                const float4* pB = (const float4*)(emb + (size_t)k1 * DIM);
#pragma unroll
                for (int i = 0; i < 16; ++i) {
                    const float4 va = pA[i], vb = pB[i];
                    eA[4 * i] = va.x; eA[4 * i + 1] = va.y; eA[4 * i + 2] = va.z; eA[4 * i + 3] = va.w;
                    eB[4 * i] = vb.x; eB[4 * i + 1] = vb.y; eB[4 * i + 2] = vb.z; eB[4 * i + 3] = vb.w;
                }
            }
            const float esqA = esq[k0];
            const float esqB = esq[k1];

            for (int ti = 0; ti < 8; ++ti) {
                const int li = 8 * b + ti;
                if (li >= nl) break;
                const int tt = list[li];
                float z[64];
                {
                    const float4* zp = (const float4*)(&z_s[tt][0]);
#pragma unroll
                    for (int i = 0; i < 16; ++i) {
                        const float4 v = zp[i];
                        z[4 * i] = v.x; z[4 * i + 1] = v.y; z[4 * i + 2] = v.z; z[4 * i + 3] = v.w;
                    }
                }
                const float zsq = zsq_s[tt];
                float accA = z[0] * eA[0];
                float accB = z[0] * eB[0];
#pragma unroll
                for (int j = 1; j < DIM; ++j) {
                    accA = fmaf(z[j], eA[j], accA);
                    accB = fmaf(z[j], eB[j], accB);
                }
                const float sA = zsq + esqA;
                const float sB = zsq + esqB;
                const float dA = fmaf(-2.0f, accA, sA);
                const float dB = fmaf(-2.0f, accB, sB);
                float dl = dA; int il = k0;
                if (dB < dl) { dl = dB; il = k1; }           // tie keeps k0 (<k1)
#pragma unroll
                for (int m = 1; m < 64; m <<= 1) {
                    const float ov = __shfl_xor(dl, m, 64);
                    const int   oi = __shfl_xor(il, m, 64);
                    if (ov < dl || (ov == dl && oi < il)) { dl = ov; il = oi; }
                }
                if (lane == 0) { d2s[s][tt] = dl; i2s[s][tt] = il; }
            }
        }
        __syncthreads();
        if (tid < 64) {
#pragma unroll
            for (int s = 0; s < 2; ++s) {
                const float dv = d2s[s][tid];
                const int iv = i2s[s][tid];
                if (dv < bD[tid] || (dv == bD[tid] && iv < bI[tid])) {
                    bD[tid] = dv; bI[tid] = iv;
                }
            }
        }
        __syncthreads();
    }

    if (tid < 64) out_idx[t0 + tid] = (float)bI[tid];
}

// ---------------------------------------------------------------------------
// Outputs: z_q = h + (q - h), loss partials (proven form).
// ---------------------------------------------------------------------------
__global__ __launch_bounds__(256) void vq_finish(const float* __restrict__ hid,
                                                 const float* __restrict__ emb,
                                                 const float* __restrict__ out_idx,
                                                 float* __restrict__ out_zq,
                                                 float* __restrict__ partials) {
#pragma clang fp contract(off)
    __shared__ float lred[4];
    const int tid = threadIdx.x;
    const int t = blockIdx.x * 256 + tid;

    const int bi = (int)out_idx[t];

    const float4* q4 = (const float4*)(emb + (size_t)bi * DIM);
    const float4* h4 = (const float4*)(hid + (size_t)t * DIM);
    float4* o4 = (float4*)(out_zq + (size_t)t * DIM);
    float lsum = 0.f;
#pragma unroll
    for (int i = 0; i < 16; ++i) {
        const float4 q = q4[i];
        const float4 h = h4[i];
        float4 zq;
        float dx;
        dx = q.x - h.x; zq.x = h.x + dx; lsum += dx * dx;
        dx = q.y - h.y; zq.y = h.y + dx; lsum += dx * dx;
        dx = q.z - h.z; zq.z = h.z + dx; lsum += dx * dx;
        dx = q.w - h.w; zq.w = h.w + dx; lsum += dx * dx;
        o4[i] = zq;
    }

#pragma unroll
    for (int off = 32; off >= 1; off >>= 1) lsum += __shfl_xor(lsum, off, 64);
    const int wid = tid >> 6;
    if ((tid & 63) == 0) lred[wid] = lsum;
    __syncthreads();
    if (tid == 0) partials[blockIdx.x] = (lred[0] + lred[1]) + (lred[2] + lred[3]);
}

__global__ __launch_bounds__(128) void loss_kernel(const float* __restrict__ partials,
                                                   float* __restrict__ out_loss) {
#pragma clang fp contract(off)
    __shared__ float s[128];
    const int t = threadIdx.x;
    s[t] = partials[t];
    __syncthreads();
    for (int off = 64; off >= 1; off >>= 1) {
        if (t < off) s[t] = s[t] + s[t + off];
        __syncthreads();
    }
    if (t == 0) {
        const float m = s[0] * (1.0f / 2097152.0f);  // exact: /2^21
        out_loss[0] = m + 0.25f * m;
    }
}

extern "C" void kernel_launch(void* const* d_in, const int* in_sizes, int n_in,
                              void* d_out, int out_size, void* d_ws, size_t ws_size,
                              hipStream_t stream) {
    const float* hid = (const float*)d_in[0];
    const float* emb = (const float*)d_in[1];
    float* out = (float*)d_out;
    float* ws  = (float*)d_ws;
    float*  esq   = ws + WS_ESQ;
    ushort* ehi   = (ushort*)(ws + WS_EHI);
    float*  parts = ws + WS_PART;
    float*  Mm    = out;            // zq region scratch; finish overwrites later

    esq_kernel<<<K_CODES / 32, 256, 0, stream>>>(emb, esq);
    pack_hi<<<K_CODES / 256, 256, 0, stream>>>(emb, ehi);
    vq_mfma<<<N_TOK / 64, 256, 0, stream>>>(hid, ehi, Mm);
    vq_select<<<N_TOK / 64, 256, 0, stream>>>(hid, emb, esq, Mm, out + IDX_OFF);
    vq_finish<<<N_TOK / 256, 256, 0, stream>>>(hid, emb, out + IDX_OFF, out, parts);
    loss_kernel<<<1, 128, 0, stream>>>(parts, out + LOSS_OFF);
}

// Round 11
// 267.419 us; speedup vs baseline: 1.8182x; 1.0565x over previous
//
#include <hip/hip_runtime.h>
#include <cfloat>

#define N_TOK   32768
#define DIM     64
#define K_CODES 8192
#define NCHK    32                 // 256-code chunks

#define IDX_OFF  (N_TOK * DIM)
#define LOSS_OFF (N_TOK * DIM + N_TOK)

// ws layout (float units): esq 8192 + ehi 262144 (1MB of bf16) + parts 128
#define WS_ESQ   0
#define WS_EHI   8192
#define WS_PART  270336

#define MRG   2e-5f     // strict slack: bound < every computed fl-d in chunk
#define DINIT 3e-5f     // init upper-bound slack (esq_max 1e-6 + 2 fl-roundings + margin)

typedef __attribute__((ext_vector_type(8)))  short bf16x8;
typedef __attribute__((ext_vector_type(16))) float f32x16;

__device__ inline ushort f2bf(float x) {          // round-to-nearest-even
    unsigned u = __float_as_uint(x);
    return (ushort)((u + 0x7FFFu + ((u >> 16) & 1u)) >> 16);
}
__device__ inline float bf2f(ushort h) { return __uint_as_float(((unsigned)h) << 16); }

// ---------------------------------------------------------------------------
// e_sq[k] = numpy-pairwise sum of squares (bitwise np order) — proven R1-R10.
// ---------------------------------------------------------------------------
__global__ __launch_bounds__(256) void esq_kernel(const float* __restrict__ emb,
                                                  float* __restrict__ esq) {
#pragma clang fp contract(off)
    const int tid = threadIdx.x;
    const int q = tid & 7;
    const int code = blockIdx.x * 32 + (tid >> 3);
    const float* row = emb + code * DIM;
    float x = row[q];
    float r = x * x;
#pragma unroll
    for (int m = 1; m < 8; ++m) {
        float y = row[q + 8 * m];
        float sq = y * y;
        r = r + sq;
    }
    r = r + __shfl_xor(r, 1, 64);
    r = r + __shfl_xor(r, 2, 64);
    r = r + __shfl_xor(r, 4, 64);
    if (q == 0) esq[code] = r;
}

// ---------------------------------------------------------------------------
// Pack embedding rows to bf16 (RN) once: ehi[k][d], code-major 128B rows.
// ---------------------------------------------------------------------------
__global__ __launch_bounds__(256) void pack_hi(const float* __restrict__ emb,
                                               ushort* __restrict__ ehi) {
#pragma clang fp contract(off)
    const int k = blockIdx.x * 256 + threadIdx.x;     // grid 32 -> 8192 codes
    const float4* ep = (const float4*)(emb + (size_t)k * DIM);
    ushort* op = ehi + (size_t)k * DIM;
#pragma unroll
    for (int i = 0; i < 8; ++i) {
        const float4 a = ep[2 * i], b = ep[2 * i + 1];
        const float zz[8] = {a.x, a.y, a.z, a.w, b.x, b.y, b.z, b.w};
        bf16x8 v;
#pragma unroll
        for (int e = 0; e < 8; ++e) v[e] = (short)f2bf(zz[e]);
        *(bf16x8*)(op + 8 * i) = v;
    }
}

// ---------------------------------------------------------------------------
// MFMA sweep (unchanged from R10, passed): A=e bf16 global, B=z hi/lo regs.
// Mm[token][chunk] f32 upper-ish dot max (eps-covered) in d_out scratch.
// ---------------------------------------------------------------------------
__global__ __launch_bounds__(256, 2) void vq_mfma(const float* __restrict__ hid,
                                                  const ushort* __restrict__ ehi,
                                                  float* __restrict__ Mm) {
#pragma clang fp contract(off)
    __shared__ float tmw[4][64];

    const int tid = threadIdx.x;
    const int lane = tid & 63;
    const int w = tid >> 6;
    const int h = lane >> 5;
    const int t0 = blockIdx.x * 64;

    bf16x8 z_hi[2][4], z_lo[2][4];
#pragma unroll
    for (int ts = 0; ts < 2; ++ts)
#pragma unroll
    for (int q = 0; q < 4; ++q) {
        const float* zp = hid + (size_t)(t0 + 32 * ts + (lane & 31)) * DIM + 16 * q + 8 * h;
        const float4 u0 = *(const float4*)zp;
        const float4 u1 = *(const float4*)(zp + 4);
        const float zz[8] = {u0.x, u0.y, u0.z, u0.w, u1.x, u1.y, u1.z, u1.w};
        bf16x8 hv, lv;
#pragma unroll
        for (int i = 0; i < 8; ++i) {
            const ushort hb = f2bf(zz[i]);
            hv[i] = (short)hb;
            lv[i] = (short)f2bf(zz[i] - bf2f(hb));
        }
        z_hi[ts][q] = hv; z_lo[ts][q] = lv;
    }

    f32x16 zc;
#pragma unroll
    for (int i = 0; i < 16; ++i) zc[i] = 0.0f;

    const ushort* abase = ehi + (size_t)(32 * w + (lane & 31)) * DIM + 8 * h;

    bf16x8 a_cur[4], a_nxt[4];
#pragma unroll
    for (int q = 0; q < 4; ++q)
        a_cur[q] = *(const bf16x8*)(abase + 16 * q);

    float wm0 = -3.0e38f, wm1 = -3.0e38f;

    for (int sc = 0; sc < 64; ++sc) {
        const int scn = (sc + 1 < 64) ? (sc + 1) : 63;
#pragma unroll
        for (int q = 0; q < 4; ++q)
            a_nxt[q] = *(const bf16x8*)(abase + (size_t)scn * 128 * DIM + 16 * q);

        f32x16 d0, d1;
#pragma unroll
        for (int q = 0; q < 4; ++q) {
            if (q == 0) {
                d0 = __builtin_amdgcn_mfma_f32_32x32x16_bf16(a_cur[0], z_hi[0][0], zc, 0, 0, 0);
                d1 = __builtin_amdgcn_mfma_f32_32x32x16_bf16(a_cur[0], z_hi[1][0], zc, 0, 0, 0);
            } else {
                d0 = __builtin_amdgcn_mfma_f32_32x32x16_bf16(a_cur[q], z_hi[0][q], d0, 0, 0, 0);
                d1 = __builtin_amdgcn_mfma_f32_32x32x16_bf16(a_cur[q], z_hi[1][q], d1, 0, 0, 0);
            }
            d0 = __builtin_amdgcn_mfma_f32_32x32x16_bf16(a_cur[q], z_lo[0][q], d0, 0, 0, 0);
            d1 = __builtin_amdgcn_mfma_f32_32x32x16_bf16(a_cur[q], z_lo[1][q], d1, 0, 0, 0);
        }
#pragma unroll
        for (int i = 0; i < 16; ++i) {
            wm0 = fmaxf(wm0, d0[i]);
            wm1 = fmaxf(wm1, d1[i]);
        }

        if (sc & 1) {
            wm0 = fmaxf(wm0, __shfl_xor(wm0, 32, 64));
            wm1 = fmaxf(wm1, __shfl_xor(wm1, 32, 64));
            if (lane < 32) {
                tmw[w][lane] = wm0;
                tmw[w][32 + lane] = wm1;
            }
            __syncthreads();
            if (tid < 64) {
                const float m4 = fmaxf(fmaxf(tmw[0][tid], tmw[1][tid]),
                                       fmaxf(tmw[2][tid], tmw[3][tid]));
                Mm[(size_t)(t0 + tid) * NCHK + (sc >> 1)] = m4;
            }
            __syncthreads();
            wm0 = -3.0e38f; wm1 = -3.0e38f;
        }
#pragma unroll
        for (int q = 0; q < 4; ++q) a_cur[q] = a_nxt[q];
    }
}

// ---------------------------------------------------------------------------
// Exact selection v2: block = 64 tokens, 4 waves. Wave w owns 64-code slice
// s=w of each surviving chunk: ONE e-row per lane in regs (64 VGPR — fits, no
// scratch), z streamed from LDS via b128 broadcast, 2 tokens per pass (ILP).
// Ref-bitwise chains; strict MRG pruning is first-index-safe. Unique writers.
// ---------------------------------------------------------------------------
__global__ __launch_bounds__(256, 2) void vq_select(const float* __restrict__ hid,
                                                    const float* __restrict__ emb,
                                                    const float* __restrict__ esq,
                                                    const float* __restrict__ Mm,
                                                    float* __restrict__ out_idx) {
#pragma clang fp contract(off)
    __shared__ float z_s[64][68];
    __shared__ float zsq_s[64];
    __shared__ float bD[64];
    __shared__ int   bI[64];
    __shared__ float d4s[4][64];
    __shared__ int   i4s[4][64];
    __shared__ int   list[64];
    __shared__ int   cnt;

    const int tid = threadIdx.x;
    const int lane = tid & 63;
    const int w = tid >> 6;
    const int t0 = blockIdx.x * 64;

    // ---- stage z into LDS ----
    {
        const int t = tid >> 2;
        const int j4 = (tid & 3) * 4;          // float4 index
        const float4* src = (const float4*)(hid + (size_t)(t0 + t) * DIM);
        float4* dst = (float4*)(&z_s[t][0]);
#pragma unroll
        for (int i = 0; i < 4; ++i) dst[j4 + i] = src[j4 + i];
    }
    __syncthreads();

    // ---- per-token: zsq (numpy pairwise), best init from Mm row max ----
    if (tid < 64) {
        const float* zr = &z_s[tid][0];
        float r[8];
#pragma unroll
        for (int q = 0; q < 8; ++q) {
            float x = zr[q]; r[q] = x * x;
#pragma unroll
            for (int m = 1; m < 8; ++m) {
                float y = zr[q + 8 * m];
                float sq = y * y;
                r[q] = r[q] + sq;
            }
        }
        const float zsq = ((r[0] + r[1]) + (r[2] + r[3])) + ((r[4] + r[5]) + (r[6] + r[7]));
        const float* mr = Mm + (size_t)(t0 + tid) * NCHK;
        float mx = mr[0];
#pragma unroll
        for (int c = 1; c < NCHK; ++c) mx = fmaxf(mx, mr[c]);
        const float eps = sqrtf(zsq) * 2.5e-6f + 2e-7f;
        zsq_s[tid] = zsq;
        bD[tid] = zsq - 2.0f * mx + 2.0f * eps + DINIT;   // >= true best fl-d
        bI[tid] = 0;
    }

    for (int c = 0; c < NCHK; ++c) {
        d4s[w][lane] = 3.0e38f;
        i4s[w][lane] = 0;
        if (tid == 0) cnt = 0;
        __syncthreads();
        if (tid < 64) {
            const float zsq = zsq_s[tid];
            const float eps = sqrtf(zsq) * 2.5e-6f + 2e-7f;
            const float m = Mm[(size_t)(t0 + tid) * NCHK + c];
            const float bound = fmaf(-2.0f, m + eps, zsq) - MRG;
            if (bound < bD[tid]) { const int p = atomicAdd(&cnt, 1); list[p] = tid; }
        }
        __syncthreads();
        const int nl = cnt;
        if (nl == 0) continue;

        {   // wave w evaluates its 64-code slice against all survivors
            const int k = c * 256 + 64 * w + lane;
            float ev[64];
            {
                const float4* pE = (const float4*)(emb + (size_t)k * DIM);
#pragma unroll
                for (int i = 0; i < 16; ++i) {
                    const float4 v = pE[i];
                    ev[4 * i] = v.x; ev[4 * i + 1] = v.y;
                    ev[4 * i + 2] = v.z; ev[4 * i + 3] = v.w;
                }
            }
            const float ek = esq[k];

            for (int p = 0; p < nl; p += 2) {
                const int tP = list[p];
                const int hasQ = (p + 1 < nl);
                const int tQ = hasQ ? list[p + 1] : tP;
                const float4* zP = (const float4*)(&z_s[tP][0]);
                const float4* zQ = (const float4*)(&z_s[tQ][0]);
                float accP, accQ;
                {
                    const float4 a = zP[0], b = zQ[0];
                    accP = a.x * ev[0];            accQ = b.x * ev[0];
                    accP = fmaf(a.y, ev[1], accP); accQ = fmaf(b.y, ev[1], accQ);
                    accP = fmaf(a.z, ev[2], accP); accQ = fmaf(b.z, ev[2], accQ);
                    accP = fmaf(a.w, ev[3], accP); accQ = fmaf(b.w, ev[3], accQ);
                }
#pragma unroll
                for (int i = 1; i < 16; ++i) {
                    const float4 a = zP[i], b = zQ[i];
                    accP = fmaf(a.x, ev[4 * i + 0], accP); accQ = fmaf(b.x, ev[4 * i + 0], accQ);
                    accP = fmaf(a.y, ev[4 * i + 1], accP); accQ = fmaf(b.y, ev[4 * i + 1], accQ);
                    accP = fmaf(a.z, ev[4 * i + 2], accP); accQ = fmaf(b.z, ev[4 * i + 2], accQ);
                    accP = fmaf(a.w, ev[4 * i + 3], accP); accQ = fmaf(b.w, ev[4 * i + 3], accQ);
                }
                float dP = fmaf(-2.0f, accP, zsq_s[tP] + ek);
                int iP = k;
#pragma unroll
                for (int m = 1; m < 64; m <<= 1) {
                    const float ov = __shfl_xor(dP, m, 64);
                    const int   oi = __shfl_xor(iP, m, 64);
                    if (ov < dP || (ov == dP && oi < iP)) { dP = ov; iP = oi; }
                }
                if (lane == 0) { d4s[w][tP] = dP; i4s[w][tP] = iP; }
                if (hasQ) {
                    float dQ = fmaf(-2.0f, accQ, zsq_s[tQ] + ek);
                    int iQ = k;
#pragma unroll
                    for (int m = 1; m < 64; m <<= 1) {
                        const float ov = __shfl_xor(dQ, m, 64);
                        const int   oi = __shfl_xor(iQ, m, 64);
                        if (ov < dQ || (ov == dQ && oi < iQ)) { dQ = ov; iQ = oi; }
                    }
                    if (lane == 0) { d4s[w][tQ] = dQ; i4s[w][tQ] = iQ; }
                }
            }
        }
        __syncthreads();
        if (tid < 64) {
#pragma unroll
            for (int s = 0; s < 4; ++s) {      // ascending slices = ascending k
                const float dv = d4s[s][tid];
                const int iv = i4s[s][tid];
                if (dv < bD[tid] || (dv == bD[tid] && iv < bI[tid])) {
                    bD[tid] = dv; bI[tid] = iv;
                }
            }
        }
        __syncthreads();
    }

    if (tid < 64) out_idx[t0 + tid] = (float)bI[tid];
}

// ---------------------------------------------------------------------------
// Outputs: z_q = h + (q - h), loss partials (proven form).
// ---------------------------------------------------------------------------
__global__ __launch_bounds__(256) void vq_finish(const float* __restrict__ hid,
                                                 const float* __restrict__ emb,
                                                 const float* __restrict__ out_idx,
                                                 float* __restrict__ out_zq,
                                                 float* __restrict__ partials) {
#pragma clang fp contract(off)
    __shared__ float lred[4];
    const int tid = threadIdx.x;
    const int t = blockIdx.x * 256 + tid;

    const int bi = (int)out_idx[t];

    const float4* q4 = (const float4*)(emb + (size_t)bi * DIM);
    const float4* h4 = (const float4*)(hid + (size_t)t * DIM);
    float4* o4 = (float4*)(out_zq + (size_t)t * DIM);
    float lsum = 0.f;
#pragma unroll
    for (int i = 0; i < 16; ++i) {
        const float4 q = q4[i];
        const float4 h = h4[i];
        float4 zq;
        float dx;
        dx = q.x - h.x; zq.x = h.x + dx; lsum += dx * dx;
        dx = q.y - h.y; zq.y = h.y + dx; lsum += dx * dx;
        dx = q.z - h.z; zq.z = h.z + dx; lsum += dx * dx;
        dx = q.w - h.w; zq.w = h.w + dx; lsum += dx * dx;
        o4[i] = zq;
    }

#pragma unroll
    for (int off = 32; off >= 1; off >>= 1) lsum += __shfl_xor(lsum, off, 64);
    const int wid = tid >> 6;
    if ((tid & 63) == 0) lred[wid] = lsum;
    __syncthreads();
    if (tid == 0) partials[blockIdx.x] = (lred[0] + lred[1]) + (lred[2] + lred[3]);
}

__global__ __launch_bounds__(128) void loss_kernel(const float* __restrict__ partials,
                                                   float* __restrict__ out_loss) {
#pragma clang fp contract(off)
    __shared__ float s[128];
    const int t = threadIdx.x;
    s[t] = partials[t];
    __syncthreads();
    for (int off = 64; off >= 1; off >>= 1) {
        if (t < off) s[t] = s[t] + s[t + off];
        __syncthreads();
    }
    if (t == 0) {
        const float m = s[0] * (1.0f / 2097152.0f);  // exact: /2^21
        out_loss[0] = m + 0.25f * m;
    }
}

extern "C" void kernel_launch(void* const* d_in, const int* in_sizes, int n_in,
                              void* d_out, int out_size, void* d_ws, size_t ws_size,
                              hipStream_t stream) {
    const float* hid = (const float*)d_in[0];
    const float* emb = (const float*)d_in[1];
    float* out = (float*)d_out;
    float* ws  = (float*)d_ws;
    float*  esq   = ws + WS_ESQ;
    ushort* ehi   = (ushort*)(ws + WS_EHI);
    float*  parts = ws + WS_PART;
    float*  Mm    = out;            // zq region scratch; finish overwrites later

    esq_kernel<<<K_CODES / 32, 256, 0, stream>>>(emb, esq);
    pack_hi<<<K_CODES / 256, 256, 0, stream>>>(emb, ehi);
    vq_mfma<<<N_TOK / 64, 256, 0, stream>>>(hid, ehi, Mm);
    vq_select<<<N_TOK / 64, 256, 0, stream>>>(hid, emb, esq, Mm, out + IDX_OFF);
    vq_finish<<<N_TOK / 256, 256, 0, stream>>>(hid, emb, out + IDX_OFF, out, parts);
    loss_kernel<<<1, 128, 0, stream>>>(parts, out + LOSS_OFF);
}